// Round 3
// baseline (325.549 us; speedup 1.0000x reference)
//
#include <hip/hip_runtime.h>
#include <hip/hip_bf16.h>

// weight_noise: out[i] = noise[i] * 0.05 * sqrt(spread_bits(trunc(x[i]*2^14))) / 2^14
// spread_bits = zero-interleave of w's bits to even positions (sum_k 4^k bit_k).
// Memory-bound streaming kernel: 12 B/elem logical HBM traffic.
// R2: same as R1 but use clang ext_vector_type for the nontemporal store
// (builtin rejects HIP_vector_type float4).

#define UNROLL 4

typedef float fvec4 __attribute__((ext_vector_type(4)));

__device__ __forceinline__ float sigma_of(float x) {
    unsigned w = (unsigned)(int)(x * 16384.0f);      // 14-bit value, trunc toward 0
    unsigned a = w;
    a = (a | (a << 8)) & 0x00FF00FFu;
    a = (a | (a << 4)) & 0x0F0F0F0Fu;
    a = (a | (a << 2)) & 0x33333333u;
    a = (a | (a << 1)) & 0x55555555u;
    return (0.05f * sqrtf((float)a)) * (1.0f / 16384.0f);
}

__global__ __launch_bounds__(256) void weight_noise_kernel(
    const fvec4* __restrict__ x4,
    const fvec4* __restrict__ n4,
    fvec4* __restrict__ o4)
{
    const int stride = gridDim.x * blockDim.x;
    const int base = blockIdx.x * blockDim.x + threadIdx.x;

    fvec4 xv[UNROLL], nv[UNROLL];
#pragma unroll
    for (int j = 0; j < UNROLL; ++j) {
        int idx = base + j * stride;
        xv[j] = x4[idx];
        nv[j] = n4[idx];
    }
#pragma unroll
    for (int j = 0; j < UNROLL; ++j) {
        fvec4 ov;
        ov.x = nv[j].x * sigma_of(xv[j].x);
        ov.y = nv[j].y * sigma_of(xv[j].y);
        ov.z = nv[j].z * sigma_of(xv[j].z);
        ov.w = nv[j].w * sigma_of(xv[j].w);
        __builtin_nontemporal_store(ov, &o4[base + j * stride]);
    }
}

// tail kernel for sizes not divisible by 256*UNROLL*4 (not hit at 4096x8192)
__global__ __launch_bounds__(256) void weight_noise_tail(
    const float* __restrict__ x,
    const float* __restrict__ nz,
    float* __restrict__ o,
    int start, int n)
{
    int i = start + blockIdx.x * blockDim.x + threadIdx.x;
    if (i < n) o[i] = nz[i] * sigma_of(x[i]);
}

extern "C" void kernel_launch(void* const* d_in, const int* in_sizes, int n_in,
                              void* d_out, int out_size, void* d_ws, size_t ws_size,
                              hipStream_t stream) {
    const float* x  = (const float*)d_in[0];
    const float* nz = (const float*)d_in[1];
    float* out = (float*)d_out;
    int n = in_sizes[0];                 // 33554432
    int count4 = n / 4;                  // 8388608 float4s
    const int block = 256;
    int per_block = block * UNROLL;      // float4s per block
    int grid = count4 / per_block;       // 8192 blocks, exact for this shape
    if (grid > 0) {
        weight_noise_kernel<<<grid, block, 0, stream>>>(
            (const fvec4*)x, (const fvec4*)nz, (fvec4*)out);
    }
    int done = grid * per_block * 4;     // elements covered
    if (done < n) {
        int rem = n - done;
        weight_noise_tail<<<(rem + block - 1) / block, block, 0, stream>>>(
            x, nz, out, done, n);
    }
}

// Round 4
// 305.520 us; speedup vs baseline: 1.0656x; 1.0656x over previous
//
#include <hip/hip_runtime.h>
#include <hip/hip_bf16.h>

// weight_noise: out[i] = noise[i] * 0.05 * sqrt(spread_bits(trunc(x[i]*2^14))) / 2^14
// spread_bits = zero-interleave of w's bits to even positions (sum_k 4^k bit_k).
// Memory-bound streaming: 12 B/elem logical.
// R3: ILP=4 with BLOCK-CONTIGUOUS layout (each block: 4 adjacent 16 KB strips
// per array) + normal cached stores. R2's 32MB-strided accesses + nt stores
// regressed (144us); this isolates the ILP lever with good DRAM locality.

#define UNROLL 4

typedef float fvec4 __attribute__((ext_vector_type(4)));

__device__ __forceinline__ float sigma_of(float x) {
    unsigned w = (unsigned)(int)(x * 16384.0f);      // 14-bit value, trunc toward 0
    unsigned a = w;
    a = (a | (a << 8)) & 0x00FF00FFu;
    a = (a | (a << 4)) & 0x0F0F0F0Fu;
    a = (a | (a << 2)) & 0x33333333u;
    a = (a | (a << 1)) & 0x55555555u;
    return (0.05f * sqrtf((float)a)) * (1.0f / 16384.0f);
}

__global__ __launch_bounds__(256) void weight_noise_kernel(
    const fvec4* __restrict__ x4,
    const fvec4* __restrict__ n4,
    fvec4* __restrict__ o4)
{
    // block covers UNROLL*256 consecutive float4s; strips are blockDim apart
    const int base = blockIdx.x * (256 * UNROLL) + threadIdx.x;

    fvec4 xv[UNROLL], nv[UNROLL];
#pragma unroll
    for (int j = 0; j < UNROLL; ++j) {
        int idx = base + j * 256;
        xv[j] = x4[idx];
        nv[j] = n4[idx];
    }
#pragma unroll
    for (int j = 0; j < UNROLL; ++j) {
        fvec4 ov;
        ov.x = nv[j].x * sigma_of(xv[j].x);
        ov.y = nv[j].y * sigma_of(xv[j].y);
        ov.z = nv[j].z * sigma_of(xv[j].z);
        ov.w = nv[j].w * sigma_of(xv[j].w);
        o4[base + j * 256] = ov;
    }
}

// tail kernel for sizes not divisible by 256*UNROLL*4 (not hit at 4096x8192)
__global__ __launch_bounds__(256) void weight_noise_tail(
    const float* __restrict__ x,
    const float* __restrict__ nz,
    float* __restrict__ o,
    int start, int n)
{
    int i = start + blockIdx.x * blockDim.x + threadIdx.x;
    if (i < n) o[i] = nz[i] * sigma_of(x[i]);
}

extern "C" void kernel_launch(void* const* d_in, const int* in_sizes, int n_in,
                              void* d_out, int out_size, void* d_ws, size_t ws_size,
                              hipStream_t stream) {
    const float* x  = (const float*)d_in[0];
    const float* nz = (const float*)d_in[1];
    float* out = (float*)d_out;
    int n = in_sizes[0];                 // 33554432
    int count4 = n / 4;                  // 8388608 float4s
    const int block = 256;
    int per_block = block * UNROLL;      // 1024 float4s per block
    int grid = count4 / per_block;       // 8192 blocks, exact here
    if (grid > 0) {
        weight_noise_kernel<<<grid, block, 0, stream>>>(
            (const fvec4*)x, (const fvec4*)nz, (fvec4*)out);
    }
    int done = grid * per_block * 4;     // elements covered
    if (done < n) {
        int rem = n - done;
        weight_noise_tail<<<(rem + block - 1) / block, block, 0, stream>>>(
            x, nz, out, done, n);
    }
}